// Round 8
// baseline (94694.598 us; speedup 1.0000x reference)
//
#include <hip/hip_runtime.h>

// GRU, round 8: hoisted igates GEMM + slim persistent kernel.
//
// Phase 1 (igates_gemm): igates[T][1536] = input @ w_ih^T + bias, tiled 64x64,
//   ~0.2 ms at full GPU. Removes ALL input streaming + igates math + its LDS
//   round trips from the serial phase.
// Phase 2 (gru_fast): 32 WGs x 1024. Wave w owns row j=wg*16+w:
//   groups 0-2 (lanes 0-47) = gates r/z/n, 32-float k-chunks, whh in regs;
//   group 3 (lanes 48-63)   = pollers, 1 16B comm line each, PERPETUAL 4-deep
//   ring (slots live across steps; stale-parity tags just fail and reissue).
//   After grp_reduce16, hr/hz/hn sit in lanes 0/16/32 of the SAME wave ->
//   gate assembly is 2 shuffles. One barrier per step. igates rows prefetched
//   one step ahead on lane 0 (192 B/WG/step, cached).
// Comm protocol unchanged (proven r1-r7): tagged 8B words {val|step},
//   2 per 16B line, parity double-buffered, sc0+sc1.
// Fallback: if ws_size < 201 MB + comm, launch the proven round-7 kernel.

#define T_STEPS    32768
#define INSZ       256
#define HSZ        512
#define NWG        32
#define POLL_GUARD 16384

typedef unsigned long long u64;
typedef unsigned int u32;
typedef u32 u32x4 __attribute__((ext_vector_type(4)));
typedef u32 u32x2 __attribute__((ext_vector_type(2)));
typedef float f32x4 __attribute__((ext_vector_type(4)));
typedef float f32x2 __attribute__((ext_vector_type(2)));

__device__ __forceinline__ float grp_reduce16(float v) {
  v += __shfl_xor(v, 1);
  v += __shfl_xor(v, 2);
  v += __shfl_xor(v, 4);
  v += __shfl_xor(v, 8);
  return v;
}

__device__ __forceinline__ int hpad(int k) { return k + 4 * (k >> 5); }

__device__ __forceinline__ void st16_sys(u64* p, u32x4 v) {
  asm volatile("global_store_dwordx4 %0, %1, off sc0 sc1" :: "v"(p), "v"(v) : "memory");
}
__device__ __forceinline__ void st8_sys(u64* p, u32x2 v) {
  asm volatile("global_store_dwordx2 %0, %1, off sc0 sc1" :: "v"(p), "v"(v) : "memory");
}

// Re-init every call (harness does not re-poison d_ws between graph replays).
__global__ void init_comm(u64* __restrict__ comm, const float* __restrict__ h0) {
  int jj = threadIdx.x;                      // 0..511
  u32 bits = __float_as_uint(h0[jj]);
  comm[jj]       = (u64)bits;                // buf0: tag 0 | h0 value
  comm[HSZ + jj] = 0xFFFFFFFF00000000ull;    // buf1: invalid tag
}

// ---------------- Phase 1: igates GEMM (64x64 tiles, K=256) ----------------
__launch_bounds__(256)
__global__ void igates_gemm(const float* __restrict__ input,
                            const float* __restrict__ w_ih,
                            const float* __restrict__ bias,
                            float* __restrict__ ig)
{
  const int t0 = blockIdx.x * 64;
  const int r0 = blockIdx.y * 64;
  const int tid = threadIdx.x;
  const int tx = tid & 15, ty = tid >> 4;    // 16x16 threads, 4x4 micro-tile
  __shared__ float As[64][68];               // [t][k], pad 4 (16B-aligned rows)
  __shared__ float Bs[64][68];               // TRANSPOSED: [k][r]
  float acc[4][4] = {};
  for (int kc = 0; kc < INSZ; kc += 64) {
    #pragma unroll
    for (int i = 0; i < 4; ++i) {
      const int rr = (tid >> 4) + 16 * i;
      f32x4 av = *(const f32x4*)&input[(size_t)(t0 + rr) * INSZ + kc + tx * 4];
      *(f32x4*)&As[rr][tx * 4] = av;
      f32x4 bv = *(const f32x4*)&w_ih[(size_t)(r0 + rr) * INSZ + kc + tx * 4];
      #pragma unroll
      for (int ci = 0; ci < 4; ++ci) Bs[tx * 4 + ci][rr] = bv[ci];
    }
    __syncthreads();
    #pragma unroll 16
    for (int kk = 0; kk < 64; ++kk) {
      float av[4], bv[4];
      #pragma unroll
      for (int a = 0; a < 4; ++a) av[a] = As[ty * 4 + a][kk];
      #pragma unroll
      for (int b = 0; b < 4; ++b) bv[b] = Bs[kk][tx * 4 + b];
      #pragma unroll
      for (int a = 0; a < 4; ++a)
        #pragma unroll
        for (int b = 0; b < 4; ++b) acc[a][b] += av[a] * bv[b];
    }
    __syncthreads();
  }
  #pragma unroll
  for (int a = 0; a < 4; ++a) {
    #pragma unroll
    for (int b = 0; b < 4; ++b) {
      const int r = r0 + tx * 4 + b;
      ig[(size_t)(t0 + ty * 4 + a) * 1536 + r] = acc[a][b] + bias[r];
    }
  }
}

// ---------------- Phase 2: slim persistent kernel ----------------
__launch_bounds__(1024, 1)
__global__ void gru_fast(const float* __restrict__ IG,     // [T][1536] (+bias)
                         const float* __restrict__ init_hidden,
                         const float* __restrict__ w_hh,
                         const float* __restrict__ bias_n,
                         u64* __restrict__ comm,
                         float* __restrict__ out)
{
  const int tid  = threadIdx.x;
  const int wg   = blockIdx.x;
  const int w    = tid >> 6;                 // wave 0..15 -> row j
  const int lane = tid & 63;
  const int grp  = lane >> 4;                // 0..2 matvec gates, 3 pollers
  const int l    = lane & 15;
  const int j    = wg * 16 + w;

  // ---- whh: gate-row (j + 512*grp), k-chunk [32l, 32l+32)  (32 f32/lane) ----
  f32x4 whh[8];
  if (grp < 3) {
    const float* rp = w_hh + (size_t)(j + 512 * grp) * HSZ + l * 32;
    #pragma unroll
    for (int c = 0; c < 8; ++c) whh[c] = *(const f32x4*)(rp + c * 4);
  }
  // ---- lane-0 state ----
  float hold = 0.f, bn_ = 0.f, ig_r = 0.f, ig_z = 0.f, ig_n = 0.f;
  if (lane == 0) {
    hold = init_hidden[j];
    bn_  = bias_n[j];
    ig_r = IG[j]; ig_z = IG[512 + j]; ig_n = IG[1024 + j];
  }

  __shared__ float h_lds[2][HSZ + 4 * (HSZ >> 5)];

  u32x4 pa, pb, pc, pd, win;
  const int pt = w * 16 + l;                 // poller line index 0..255

#define ISSUE(Rr) \
  asm volatile("global_load_dwordx4 %0, %1, off sc0 sc1" : "=&v"(Rr) : "v"(lp) : "memory")
#define CHECK(Rr) \
  asm volatile("s_waitcnt vmcnt(3)" : "+v"(Rr)); \
  __builtin_amdgcn_sched_barrier(0); \
  if ((Rr[1] == tt && Rr[3] == tt) || --guard == 0) { win = Rr; break; } \
  ISSUE(Rr)

  // prologue: fill the perpetual ring (poller lanes only)
  if (grp == 3) {
    const u64* lp = comm + 2 * pt;           // parity-0 buffer, step 0
    ISSUE(pa); ISSUE(pb); ISSUE(pc); ISSUE(pd);
  }

  for (int t = 0; t < T_STEPS; ++t) {
    const int p  = t & 1;
    const u32 tt = (u32)t;

    // ---- poll h_t (perpetual ring; stale-parity tags fail & reissue) ----
    if (grp == 3) {
      const u64* lp = comm + (size_t)p * HSZ + 2 * pt;
      int guard = POLL_GUARD;
      win = pa;
      for (;;) {
        CHECK(pa);
        CHECK(pb);
        CHECK(pc);
        CHECK(pd);
      }
      f32x2 hv;
      hv[0] = __uint_as_float(win[0]);
      hv[1] = __uint_as_float(win[2]);
      *(f32x2*)&h_lds[p][hpad(2 * pt)] = hv;
    }
    __syncthreads();   // the ONLY barrier per step

    // ---- hh matvec: 32 MAC per lane (groups 0-2), whh register-resident ----
    float a = 0.f;
    if (grp < 3) {
      const float* hp = &h_lds[p][l * 36];   // hpad(32l); grp1/2 broadcast-read
      #pragma unroll
      for (int c = 0; c < 8; ++c) {
        f32x4 hv4 = *(const f32x4*)(hp + c * 4);
        #pragma unroll
        for (int u = 0; u < 4; ++u) a += whh[c][u] * hv4[u];
      }
      a = grp_reduce16(a);
    }
    // gate assembly: hr/hz/hn live in lanes 0/16/32 of THIS wave
    const float hz = __shfl(a, 16);
    const float hn = __shfl(a, 32);

    if (lane == 0) {
      const float reset = __builtin_amdgcn_rcpf(1.0f + __expf(-(ig_r + a)));
      const float upd   = __builtin_amdgcn_rcpf(1.0f + __expf(-(ig_z + hz)));
      const float e2    = __expf(2.0f * (ig_n + reset * (hn + bn_)));
      const float newv  = 1.0f - 2.0f * __builtin_amdgcn_rcpf(1.0f + e2);
      const float hnew  = newv + upd * (hold - newv);
      hold = hnew;
      u32x2 pk;
      pk[0] = __float_as_uint(hnew);
      pk[1] = (u32)(t + 1);
      st8_sys(comm + (size_t)((t + 1) & 1) * HSZ + j, pk);
      if (wg == 0 && w == 0) out[t] = hnew;
      // prefetch igates row for t+1 (cached loads; used after next poll+matvec)
      const size_t base = (size_t)((t + 1 < T_STEPS) ? (t + 1) : t) * 1536;
      ig_r = IG[base + j]; ig_z = IG[base + 512 + j]; ig_n = IG[base + 1024 + j];
    }
  }
#undef ISSUE
#undef CHECK
}

// ---------------- Fallback: proven round-7 kernel (fused igates) ----------------
#define TPB_FB 1024
__device__ __forceinline__ int xpad(int k) { return k + ((k >> 4) << 2); }

__launch_bounds__(TPB_FB, 1)
__global__ void gru_persistent_fb(const float* __restrict__ input,
                                  const float* __restrict__ init_hidden,
                                  const float* __restrict__ w_ih,
                                  const float* __restrict__ w_hh,
                                  const float* __restrict__ bias,
                                  const float* __restrict__ bias_n,
                                  u64* __restrict__ comm,
                                  float* __restrict__ out)
{
  const int tid = threadIdx.x;
  const int wg  = blockIdx.x;
  const int g   = tid >> 4;
  const int l   = tid & 15;
  const bool mv = (g < 48);
  const int R   = wg * 16 + (g & 15) + 512 * (g >> 4);

  f32x4 whh[8];
  f32x4 wih[4];
  if (mv) {
    const float* rp = w_hh + (size_t)R * HSZ + l * 32;
    #pragma unroll
    for (int c = 0; c < 8; ++c) whh[c] = *(const f32x4*)(rp + c * 4);
    const float* rp2 = w_ih + (size_t)R * INSZ + l * 16;
    #pragma unroll
    for (int c = 0; c < 4; ++c) wih[c] = *(const f32x4*)(rp2 + c * 4);
  }
  float hold = 0.f, b_r = 0.f, b_z = 0.f, b_n = 0.f, bn = 0.f;
  if (tid < 16) {
    const int j = wg * 16 + tid;
    hold = init_hidden[j];
    b_r  = bias[j]; b_z = bias[j + 512]; b_n = bias[j + 1024];
    bn   = bias_n[j];
  }
  __shared__ float h_lds[2][HSZ + 4 * (HSZ >> 5)];
  __shared__ float gsum[48];
  __shared__ float isum[2][48];
  __shared__ float xstage[INSZ + (INSZ >> 4) * 4];

  if (tid >= 64 && tid < 128) {
    const int s = tid - 64;
    f32x4 v = *(const f32x4*)(input + s * 4);
    *(f32x4*)&xstage[xpad(s * 4)] = v;
  }
  __syncthreads();
  if (mv) {
    float a = 0.f;
    #pragma unroll
    for (int c = 0; c < 4; ++c) {
      f32x4 xv = *(const f32x4*)&xstage[20 * l + 4 * c];
      #pragma unroll
      for (int u = 0; u < 4; ++u) a += wih[c][u] * xv[u];
    }
    a = grp_reduce16(a);
    if (l == 0) isum[0][g] = a;
  }
  const bool poller = (tid >= 768);
  const int  pt     = tid - 768;
  u32x4 pa, pb, pc, pd, win;

#define ISSUE(Rr) \
  asm volatile("global_load_dwordx4 %0, %1, off sc0 sc1" : "=&v"(Rr) : "v"(lp) : "memory")
#define CHECK(Rr) \
  asm volatile("s_waitcnt vmcnt(3)" : "+v"(Rr)); \
  __builtin_amdgcn_sched_barrier(0); \
  if ((Rr[1] == tt && Rr[3] == tt) || --guard == 0) { win = Rr; break; } \
  ISSUE(Rr)

  for (int t = 0; t < T_STEPS; ++t) {
    const int p  = t & 1;
    const u32 tt = (u32)t;
    f32x4 xnew = {0.f, 0.f, 0.f, 0.f};
    if (tid >= 64 && tid < 128) {
      const int tn = (t + 1 < T_STEPS) ? (t + 1) : (T_STEPS - 1);
      xnew = *(const f32x4*)(input + (size_t)tn * INSZ + (tid - 64) * 4);
    }
    if (poller) {
      const u64* lp = comm + (size_t)p * HSZ + 2 * pt;
      ISSUE(pa); ISSUE(pb); ISSUE(pc); ISSUE(pd);
      int guard = POLL_GUARD;
      win = pa;
      for (;;) {
        CHECK(pa);
        CHECK(pb);
        CHECK(pc);
        CHECK(pd);
      }
      f32x2 hv;
      hv[0] = __uint_as_float(win[0]);
      hv[1] = __uint_as_float(win[2]);
      *(f32x2*)&h_lds[p][hpad(2 * pt)] = hv;
    }
    __syncthreads();
    if (mv) {
      float a = 0.f;
      const float* hp = &h_lds[p][l * 36];
      #pragma unroll
      for (int c = 0; c < 8; ++c) {
        f32x4 hv4 = *(const f32x4*)(hp + c * 4);
        #pragma unroll
        for (int u = 0; u < 4; ++u) a += whh[c][u] * hv4[u];
      }
      a = grp_reduce16(a);
      if (l == 0) gsum[g] = a;
    }
    if (tid >= 64 && tid < 128) *(f32x4*)&xstage[xpad((tid - 64) * 4)] = xnew;
    __syncthreads();
    if (tid < 16) {
      const int j = tid;
      const float hr = gsum[j], hz = gsum[16 + j], hn = gsum[32 + j];
      const float i_r = isum[p][j], i_z = isum[p][16 + j], i_n = isum[p][32 + j];
      const float reset = __builtin_amdgcn_rcpf(1.0f + __expf(-(i_r + b_r + hr)));
      const float upd   = __builtin_amdgcn_rcpf(1.0f + __expf(-(i_z + b_z + hz)));
      const float e2    = __expf(2.0f * (i_n + b_n + reset * (hn + bn)));
      const float newv  = 1.0f - 2.0f * __builtin_amdgcn_rcpf(1.0f + e2);
      const float hnew  = newv + upd * (hold - newv);
      hold = hnew;
      const float hpair = __shfl(hnew, tid + 1);
      if ((j & 1) == 0) {
        u64* nbuf = comm + (size_t)((t + 1) & 1) * HSZ;
        u32x4 pk;
        pk[0] = __float_as_uint(hnew);  pk[1] = (u32)(t + 1);
        pk[2] = __float_as_uint(hpair); pk[3] = (u32)(t + 1);
        st16_sys(&nbuf[wg * 16 + j], pk);
        if (wg == 0 && j == 0) out[t] = hnew;
      }
    }
    if (mv) {
      float a2 = 0.f;
      #pragma unroll
      for (int c = 0; c < 4; ++c) {
        f32x4 xv = *(const f32x4*)&xstage[20 * l + 4 * c];
        #pragma unroll
        for (int u = 0; u < 4; ++u) a2 += wih[c][u] * xv[u];
      }
      a2 = grp_reduce16(a2);
      if (l == 0) isum[(t + 1) & 1][g] = a2;
    }
  }
#undef ISSUE
#undef CHECK
}

extern "C" void kernel_launch(void* const* d_in, const int* in_sizes, int n_in,
                              void* d_out, int out_size, void* d_ws, size_t ws_size,
                              hipStream_t stream) {
  const float* input  = (const float*)d_in[0];
  const float* h0     = (const float*)d_in[1];
  const float* w_ih   = (const float*)d_in[2];
  const float* w_hh   = (const float*)d_in[3];
  const float* bias   = (const float*)d_in[4];
  const float* bias_n = (const float*)d_in[5];
  float* out = (float*)d_out;

  const size_t IG_BYTES = (size_t)T_STEPS * 1536 * sizeof(float);  // 201.3 MB

  if (ws_size >= IG_BYTES + 16384) {
    float* ig  = (float*)d_ws;
    u64*  comm = (u64*)((char*)d_ws + IG_BYTES);
    hipLaunchKernelGGL(init_comm, dim3(1), dim3(HSZ), 0, stream, comm, h0);
    hipLaunchKernelGGL(igates_gemm, dim3(T_STEPS / 64, 1536 / 64), dim3(256),
                       0, stream, input, w_ih, bias, ig);
    hipLaunchKernelGGL(gru_fast, dim3(NWG), dim3(1024), 0, stream,
                       ig, h0, w_hh, bias_n, comm, out);
  } else {
    u64* comm = (u64*)d_ws;
    hipLaunchKernelGGL(init_comm, dim3(1), dim3(HSZ), 0, stream, comm, h0);
    hipLaunchKernelGGL(gru_persistent_fb, dim3(NWG), dim3(TPB_FB), 0, stream,
                       input, h0, w_ih, w_hh, bias, bias_n, comm, out);
  }
}